// Round 7
// baseline (272.293 us; speedup 1.0000x reference)
//
#include <hip/hip_runtime.h>
#include <hip/hip_bf16.h>

// Problem constants
#define T_DIM 8192
#define IN_DIM 1024
#define RES_DIM 4096

typedef unsigned short u16;
typedef __bf16 bf16x8 __attribute__((ext_vector_type(8)));
typedef float f32x4 __attribute__((ext_vector_type(4)));
typedef float f32x16 __attribute__((ext_vector_type(16)));

// ---------- helpers ----------
__device__ __forceinline__ u16 f2bf(float f) {
    unsigned u = __float_as_uint(f);
    return (u16)((u + 0x7FFFu + ((u >> 16) & 1u)) >> 16);   // RNE
}
__device__ __forceinline__ float bf2f(u16 h) {
    return __uint_as_float(((unsigned)h) << 16);
}

__device__ __forceinline__ float tanh_fast(float z) {
    z = fminf(15.0f, fmaxf(-15.0f, z));          // avoid exp overflow
    float e = __expf(2.0f * z);
    float inv = __builtin_amdgcn_rcpf(e + 1.0f);
    return fmaf(-2.0f, inv, 1.0f);
}

__device__ __forceinline__ void stage16(const u16* g, u16* l) {
    __builtin_amdgcn_global_load_lds(
        (const __attribute__((address_space(1))) void*)g,
        (__attribute__((address_space(3))) void*)l, 16, 0, 0);
}

// ---------- convert: f32 row-major [rows][1024] -> tiled hi/lo bf16 (round-1 verified) ----------
// Tile (rt, kt): rows rt*128..+128, k kt*32..+32. In-tile elem = kq*1024 + row*8 + e,
// k = kq*8 + e (kq in [0,4)). Chunk c = ((rt*32+kt)*4+kq)*128 + row.
// For 32x32x16 fragments: kq = ks*2 + (lane>>5) gives k = ks*16 + (lane>>5)*8 + e.
__global__ void convert_tiled(const float* __restrict__ src, u16* __restrict__ hi,
                              u16* __restrict__ lo, int nchunks) {
    for (int c = blockIdx.x * blockDim.x + threadIdx.x; c < nchunks;
         c += gridDim.x * blockDim.x) {
        int row = c & 127;
        int kq  = (c >> 7) & 3;
        int kt  = (c >> 9) & 31;
        int rt  = c >> 14;
        const float* s = src + (size_t)(rt * 128 + row) * 1024 + kt * 32 + kq * 8;
        float4 f0 = *(const float4*)s;
        float4 f1 = *(const float4*)(s + 4);
        float f[8] = {f0.x, f0.y, f0.z, f0.w, f1.x, f1.y, f1.z, f1.w};
        alignas(16) u16 hv[8];
        alignas(16) u16 lv[8];
#pragma unroll
        for (int e = 0; e < 8; ++e) {
            u16 h = f2bf(f[e]);
            hv[e] = h;
            lv[e] = f2bf(f[e] - bf2f(h));
        }
        *(uint4*)(hi + (size_t)c * 8) = *(const uint4*)hv;
        *(uint4*)(lo + (size_t)c * 8) = *(const uint4*)lv;
    }
}

// ---------- GEMM: hi/lo 3-pass bf16 MFMA, 128x128 tile, A direct global->VGPR ----------
// Round-5 structure/layouts, but A fragments are loaded straight from global (the
// tiled layout makes each fragment a contiguous coalesced 512B x2 read, L2/L3-hot),
// removing half the ds_read_b128 traffic (the measured serialization partner of MFMA).
// Only B lives in LDS (16 KiB, single-buffer 2-barrier loop).
__global__ __launch_bounds__(256, 4)   // force <=128 VGPR: 16 waves/CU, 4 blocks resident
void gemm_adirect(const u16* __restrict__ Ah, const u16* __restrict__ Al,
                  const u16* __restrict__ Bh, const u16* __restrict__ Bl,
                  float* __restrict__ C) {
    __shared__ __attribute__((aligned(16))) u16 sBh[4096];
    __shared__ __attribute__((aligned(16))) u16 sBl[4096];

    const int tid  = threadIdx.x;
    const int lane = tid & 63;
    const int wave = tid >> 6;
    const int wr = wave >> 1, wc = wave & 1;
    const int bm = blockIdx.x, bn = blockIdx.y;

    f32x16 acc[2][2] = {};   // [mf][nf], each 32x32

    const int l31 = lane & 31;
    const int kgl = lane >> 5;
    // A fragment elem offset within tile: (ks*2+kgl)*1024 + (wr*64+mf*32+l31)*8
    const int afrag = kgl * 1024 + (wr * 64 + l31) * 8;
    const int boff  = kgl * 1024 + (wc * 64 + l31) * 8;

    const size_t bbase = (size_t)bn * 32 * 4096;

#pragma unroll 1
    for (int kt = 0; kt < 32; ++kt) {
        const size_t abase = ((size_t)(bm * 32 + kt)) * 4096;

        // A fragments: direct global loads (issued before both barriers -> long cover)
        bf16x8 ah[2][2], al8[2][2];   // [mf][ks]
#pragma unroll
        for (int mf = 0; mf < 2; ++mf)
#pragma unroll
            for (int ks = 0; ks < 2; ++ks) {
                const size_t ao = abase + afrag + ks * 2048 + mf * 256;
                ah[mf][ks]  = *(const bf16x8*)(Ah + ao);
                al8[mf][ks] = *(const bf16x8*)(Al + ao);
            }

        __syncthreads();   // WAR: previous iteration's B reads done
        {
            const u16* gBh = Bh + bbase + (size_t)kt * 4096;
            const u16* gBl = Bl + bbase + (size_t)kt * 4096;
#pragma unroll
            for (int i = 0; i < 2; ++i) {
                int c  = tid + i * 256;       // chunk in [0,512)
                int wb = (c & ~63) * 8;       // wave-uniform LDS elem base
                int ge = c * 8;
                stage16(gBh + ge, sBh + wb);
                stage16(gBl + ge, sBl + wb);
            }
        }
        __syncthreads();   // staging visible (barrier drains vmcnt; A loads done too)

        bf16x8 bh[2][2], bl8[2][2];   // [nf][ks]
#pragma unroll
        for (int nf = 0; nf < 2; ++nf)
#pragma unroll
            for (int ks = 0; ks < 2; ++ks) {
                bh[nf][ks]  = *(const bf16x8*)(sBh + boff + ks * 2048 + nf * 256);
                bl8[nf][ks] = *(const bf16x8*)(sBl + boff + ks * 2048 + nf * 256);
            }
#pragma unroll
        for (int mf = 0; mf < 2; ++mf)
#pragma unroll
            for (int nf = 0; nf < 2; ++nf)
#pragma unroll
                for (int ks = 0; ks < 2; ++ks) {
                    acc[mf][nf] = __builtin_amdgcn_mfma_f32_32x32x16_bf16(
                        ah[mf][ks], bh[nf][ks], acc[mf][nf], 0, 0, 0);
                    acc[mf][nf] = __builtin_amdgcn_mfma_f32_32x32x16_bf16(
                        ah[mf][ks], bl8[nf][ks], acc[mf][nf], 0, 0, 0);
                    acc[mf][nf] = __builtin_amdgcn_mfma_f32_32x32x16_bf16(
                        al8[mf][ks], bh[nf][ks], acc[mf][nf], 0, 0, 0);
                }
    }

    // epilogue: 32x32 C/D layout col = lane&31, row = (reg&3) + 8*(reg>>2) + 4*(lane>>5)
    // [m74/m101 verified, round-5/6 proven]
    const size_t t0 = (size_t)bm * 128 + wr * 64;
    const size_t c0 = (size_t)bn * 128 + wc * 64;
#pragma unroll
    for (int mf = 0; mf < 2; ++mf)
#pragma unroll
        for (int nf = 0; nf < 2; ++nf) {
            float* cp = C + (t0 + mf * 32) * RES_DIM + (c0 + nf * 32 + l31);
#pragma unroll
            for (int r = 0; r < 16; ++r) {
                int row = (r & 3) + 8 * (r >> 2) + 4 * kgl;
                cp[(size_t)row * RES_DIM] = acc[mf][nf][r];
            }
        }
}

// ---------- fallback fp32 GEMM (only if ws too small) ----------
__global__ __launch_bounds__(256)
void gemm_f32(const float* __restrict__ A, const float* __restrict__ B, float* __restrict__ C) {
    __shared__ float sAf[64][33];
    __shared__ float sBf[64][33];
    const int tid = threadIdx.x;
    const int tx = tid & 15, ty = tid >> 4;
    const size_t t0 = (size_t)blockIdx.x * 64;
    const size_t r0 = (size_t)blockIdx.y * 64;
    const int lrow = tid >> 2;
    const int lcol = (tid & 3) * 8;
    float acc[4][4] = {};
    for (int k0 = 0; k0 < IN_DIM; k0 += 32) {
        float4 a0 = *(const float4*)&A[(t0 + lrow) * IN_DIM + k0 + lcol];
        float4 a1 = *(const float4*)&A[(t0 + lrow) * IN_DIM + k0 + lcol + 4];
        float4 b0 = *(const float4*)&B[(r0 + lrow) * IN_DIM + k0 + lcol];
        float4 b1 = *(const float4*)&B[(r0 + lrow) * IN_DIM + k0 + lcol + 4];
        __syncthreads();
        sAf[lrow][lcol + 0] = a0.x; sAf[lrow][lcol + 1] = a0.y;
        sAf[lrow][lcol + 2] = a0.z; sAf[lrow][lcol + 3] = a0.w;
        sAf[lrow][lcol + 4] = a1.x; sAf[lrow][lcol + 5] = a1.y;
        sAf[lrow][lcol + 6] = a1.z; sAf[lrow][lcol + 7] = a1.w;
        sBf[lrow][lcol + 0] = b0.x; sBf[lrow][lcol + 1] = b0.y;
        sBf[lrow][lcol + 2] = b0.z; sBf[lrow][lcol + 3] = b0.w;
        sBf[lrow][lcol + 4] = b1.x; sBf[lrow][lcol + 5] = b1.y;
        sBf[lrow][lcol + 6] = b1.z; sBf[lrow][lcol + 7] = b1.w;
        __syncthreads();
#pragma unroll
        for (int kk = 0; kk < 32; ++kk) {
            float av[4], bv[4];
#pragma unroll
            for (int i = 0; i < 4; ++i) av[i] = sAf[ty * 4 + i][kk];
#pragma unroll
            for (int j = 0; j < 4; ++j) bv[j] = sBf[tx * 4 + j][kk];
#pragma unroll
            for (int i = 0; i < 4; ++i)
#pragma unroll
                for (int j = 0; j < 4; ++j) acc[i][j] = fmaf(av[i], bv[j], acc[i][j]);
        }
    }
#pragma unroll
    for (int i = 0; i < 4; ++i)
#pragma unroll
        for (int j = 0; j < 4; ++j)
            C[(t0 + ty * 4 + i) * IN_DIM * 0 + (t0 + ty * 4 + i) * RES_DIM + r0 + tx * 4 + j] = acc[i][j];
}

// ---------- scan part A: warmup seeds (float2: 2 independent columns per thread) ----------
__global__ void warmup2_kernel(const float* __restrict__ U, const float* __restrict__ d,
                               float* __restrict__ sinit, int C, int W, int NC) {
    int g = blockIdx.x * blockDim.x + threadIdx.x;
    if (g >= NC * (RES_DIM / 2)) return;
    int c = g >> 11;              // / 2048
    int r2 = g & 2047;
    float2 s = make_float2(0.0f, 0.0f);
    if (c > 0) {
        float2 dr = ((const float2*)d)[r2];
        const float2* p = (const float2*)U + (size_t)(c * C - W) * 2048 + r2;
        constexpr int PF = 8;
        float2 buf[PF];
#pragma unroll
        for (int i = 0; i < PF; ++i) buf[i] = p[(size_t)i * 2048];
        for (int t = 0; t < W; t += PF) {
#pragma unroll
            for (int j = 0; j < PF; ++j) {
                float2 u = buf[j];
                int tn = t + j + PF;
                if (tn < W) buf[j] = p[(size_t)tn * 2048];
                s.x = tanh_fast(fmaf(dr.x, s.x, u.x));
                s.y = tanh_fast(fmaf(dr.y, s.y, u.y));
            }
        }
    }
    ((float2*)sinit)[g] = s;
}

// ---------- scan part B: in-place chunked scan (float2) ----------
__global__ void scan2_kernel(float* __restrict__ U, const float* __restrict__ d,
                             const float* __restrict__ sinit, int C, int NC) {
    int g = blockIdx.x * blockDim.x + threadIdx.x;
    if (g >= NC * (RES_DIM / 2)) return;
    int c = g >> 11;
    int r2 = g & 2047;
    float2 dr = ((const float2*)d)[r2];
    float2 s = (c == 0) ? make_float2(0.0f, 0.0f) : ((const float2*)sinit)[g];
    float2* p = (float2*)U + (size_t)c * C * 2048 + r2;
    constexpr int PF = 8;
    float2 buf[PF];
#pragma unroll
    for (int i = 0; i < PF; ++i) buf[i] = p[(size_t)i * 2048];
    for (int t = 0; t < C; t += PF) {
#pragma unroll
        for (int j = 0; j < PF; ++j) {
            float2 u = buf[j];
            int tn = t + j + PF;
            if (tn < C) buf[j] = p[(size_t)tn * 2048];   // prefetch ahead of the chain
            s.x = tanh_fast(fmaf(dr.x, s.x, u.x));
            s.y = tanh_fast(fmaf(dr.y, s.y, u.y));
            p[(size_t)(t + j) * 2048] = s;
        }
    }
}

// ---------- launch ----------
extern "C" void kernel_launch(void* const* d_in, const int* in_sizes, int n_in,
                              void* d_out, int out_size, void* d_ws, size_t ws_size,
                              hipStream_t stream) {
    const float* x    = (const float*)d_in[0];   // [T, 1024, 1]
    const float* W_in = (const float*)d_in[1];   // [4096, 1024]
    const float* dvec = (const float*)d_in[2];   // [4096]
    float* out = (float*)d_out;                  // [T, 4096]

    constexpr int NC   = 64;
    constexpr int CHK  = T_DIM / NC;   // 128
    constexpr int WARM = 64;

    const size_t szX = (size_t)T_DIM * IN_DIM * sizeof(u16);   // 16 MiB each (hi, lo)
    const size_t szW = (size_t)RES_DIM * IN_DIM * sizeof(u16); // 8 MiB each
    const size_t szS = (size_t)NC * RES_DIM * sizeof(float);   // 1 MiB

    if (ws_size >= 2 * szX + 2 * szW + szS) {
        u16* Xh = (u16*)d_ws;
        u16* Xl = Xh + (size_t)T_DIM * IN_DIM;
        u16* Wh = Xl + (size_t)T_DIM * IN_DIM;
        u16* Wl = Wh + (size_t)RES_DIM * IN_DIM;
        float* sinit = (float*)(Wl + (size_t)RES_DIM * IN_DIM);

        convert_tiled<<<2048, 256, 0, stream>>>(x, Xh, Xl, T_DIM * IN_DIM / 8);
        convert_tiled<<<1024, 256, 0, stream>>>(W_in, Wh, Wl, RES_DIM * IN_DIM / 8);
        gemm_adirect<<<dim3(T_DIM / 128, RES_DIM / 128), 256, 0, stream>>>(Xh, Xl, Wh, Wl, out);
        warmup2_kernel<<<NC * (RES_DIM / 2) / 256, 256, 0, stream>>>(out, dvec, sinit, CHK, WARM, NC);
        scan2_kernel<<<NC * (RES_DIM / 2) / 256, 256, 0, stream>>>(out, dvec, sinit, CHK, NC);
    } else {
        gemm_f32<<<dim3(T_DIM / 64, RES_DIM / 64), 256, 0, stream>>>(x, W_in, out);
        if (ws_size >= szS) {
            float* sinit = (float*)d_ws;
            warmup2_kernel<<<NC * (RES_DIM / 2) / 256, 256, 0, stream>>>(out, dvec, sinit, CHK, WARM, NC);
            scan2_kernel<<<NC * (RES_DIM / 2) / 256, 256, 0, stream>>>(out, dvec, sinit, CHK, NC);
        } else {
            scan2_kernel<<<(RES_DIM / 2) / 256, 256, 0, stream>>>(out, dvec, nullptr, T_DIM, 1);
        }
    }
}

// Round 8
// 216.906 us; speedup vs baseline: 1.2554x; 1.2554x over previous
//
#include <hip/hip_runtime.h>
#include <hip/hip_bf16.h>

// Problem constants
#define T_DIM 8192
#define IN_DIM 1024
#define RES_DIM 4096

typedef unsigned short u16;
typedef _Float16 f16;
typedef f16 f16x8 __attribute__((ext_vector_type(8)));
typedef float f32x4 __attribute__((ext_vector_type(4)));
typedef float f32x16 __attribute__((ext_vector_type(16)));

// ---------- helpers ----------
__device__ __forceinline__ float tanh_fast(float z) {
    z = fminf(15.0f, fmaxf(-15.0f, z));          // avoid exp overflow
    float e = __expf(2.0f * z);
    float inv = __builtin_amdgcn_rcpf(e + 1.0f);
    return fmaf(-2.0f, inv, 1.0f);
}

__device__ __forceinline__ void stage16(const u16* g, u16* l) {
    __builtin_amdgcn_global_load_lds(
        (const __attribute__((address_space(1))) void*)g,
        (__attribute__((address_space(3))) void*)l, 16, 0, 0);
}

// ---------- converts: f32 row-major [rows][1024] -> tiled fp16 (verified tile mapping) ----------
// Tile (rt, kt): rows rt*128..+128, k kt*32..+32. In-tile elem = kq*1024 + row*8 + e,
// k = kq*8 + e (kq in [0,4)). Chunk c = ((rt*32+kt)*4+kq)*128 + row.
// For 32x32x16 fragments: kq = ks*2 + (lane>>5) gives k = ks*16 + (lane>>5)*8 + e.
__global__ void convert_f16_pair(const float* __restrict__ src, u16* __restrict__ hi,
                                 u16* __restrict__ lo, int nchunks) {
    for (int c = blockIdx.x * blockDim.x + threadIdx.x; c < nchunks;
         c += gridDim.x * blockDim.x) {
        int row = c & 127;
        int kq  = (c >> 7) & 3;
        int kt  = (c >> 9) & 31;
        int rt  = c >> 14;
        const float* s = src + (size_t)(rt * 128 + row) * 1024 + kt * 32 + kq * 8;
        float4 f0 = *(const float4*)s;
        float4 f1 = *(const float4*)(s + 4);
        float f[8] = {f0.x, f0.y, f0.z, f0.w, f1.x, f1.y, f1.z, f1.w};
        alignas(16) u16 hv[8];
        alignas(16) u16 lv[8];
#pragma unroll
        for (int e = 0; e < 8; ++e) {
            f16 h = (f16)f[e];
            f16 l = (f16)(f[e] - (float)h);
            hv[e] = *(const u16*)&h;
            lv[e] = *(const u16*)&l;
        }
        *(uint4*)(hi + (size_t)c * 8) = *(const uint4*)hv;
        *(uint4*)(lo + (size_t)c * 8) = *(const uint4*)lv;
    }
}

__global__ void convert_f16_single(const float* __restrict__ src, u16* __restrict__ dst,
                                   int nchunks) {
    for (int c = blockIdx.x * blockDim.x + threadIdx.x; c < nchunks;
         c += gridDim.x * blockDim.x) {
        int row = c & 127;
        int kq  = (c >> 7) & 3;
        int kt  = (c >> 9) & 31;
        int rt  = c >> 14;
        const float* s = src + (size_t)(rt * 128 + row) * 1024 + kt * 32 + kq * 8;
        float4 f0 = *(const float4*)s;
        float4 f1 = *(const float4*)(s + 4);
        float f[8] = {f0.x, f0.y, f0.z, f0.w, f1.x, f1.y, f1.z, f1.w};
        alignas(16) u16 hv[8];
#pragma unroll
        for (int e = 0; e < 8; ++e) {
            f16 h = (f16)f[e];
            hv[e] = *(const u16*)&h;
        }
        *(uint4*)(dst + (size_t)c * 8) = *(const uint4*)hv;
    }
}

// ---------- GEMM: 2-pass fp16 MFMA (Xh*W + Xl*W), 256x128 tile, round-6 structure ----------
// Proven single-buffer 2-barrier loop, verified layouts/epilogue; 16 MFMA + 12 ds_read_b128
// per wave per kt (was 24 + 16), 40 KiB LDS.
__global__ __launch_bounds__(512)
void gemm_f16_2p(const u16* __restrict__ Xh, const u16* __restrict__ Xl,
                 const u16* __restrict__ Wf, float* __restrict__ C) {
    __shared__ __attribute__((aligned(16))) u16 sAh[2][4096];
    __shared__ __attribute__((aligned(16))) u16 sAl[2][4096];
    __shared__ __attribute__((aligned(16))) u16 sW[4096];

    const int tid  = threadIdx.x;
    const int lane = tid & 63;
    const int w    = tid >> 6;
    const int wr = w >> 1;          // 0..3: 64-row band within 256
    const int wc = w & 1;           // 0..1: 64-col band within 128
    const int bm = blockIdx.x, bn = blockIdx.y;

    f32x16 acc[2][2] = {};   // [mf][nf], each 32x32

    const int l31 = lane & 31;
    const int kgl = lane >> 5;
    const int asub = wr >> 1;            // which 128-row sub-tile
    const int arow = (wr & 1) * 64;      // row base within sub-tile

    const int wb = (tid & ~63) * 8;      // wave-uniform LDS elem base (512 thr -> 4096 elems)

    for (int kt = 0; kt < 32; ++kt) {
        const size_t a0 = ((size_t)((bm * 2 + 0) * 32 + kt)) * 4096 + tid * 8;
        const size_t a1 = ((size_t)((bm * 2 + 1) * 32 + kt)) * 4096 + tid * 8;
        const size_t bb = ((size_t)(bn * 32 + kt)) * 4096 + tid * 8;
        __syncthreads();   // previous iteration's LDS reads done (WAR)
        stage16(Xh + a0, &sAh[0][0] + wb);
        stage16(Xh + a1, &sAh[1][0] + wb);
        stage16(Xl + a0, &sAl[0][0] + wb);
        stage16(Xl + a1, &sAl[1][0] + wb);
        stage16(Wf + bb, &sW[0] + wb);
        __syncthreads();   // staging visible (compiler drains vmcnt at barrier)

        f16x8 ah[2][2], al8[2][2], bw[2][2];   // [mf|nf][ks]
#pragma unroll
        for (int mf = 0; mf < 2; ++mf)
#pragma unroll
            for (int ks = 0; ks < 2; ++ks) {
                int ao = (ks * 2 + kgl) * 1024 + (arow + mf * 32 + l31) * 8;
                ah[mf][ks]  = *(const f16x8*)(&sAh[asub][0] + ao);
                al8[mf][ks] = *(const f16x8*)(&sAl[asub][0] + ao);
            }
#pragma unroll
        for (int nf = 0; nf < 2; ++nf)
#pragma unroll
            for (int ks = 0; ks < 2; ++ks) {
                int bo = (ks * 2 + kgl) * 1024 + (wc * 64 + nf * 32 + l31) * 8;
                bw[nf][ks] = *(const f16x8*)(&sW[0] + bo);
            }
#pragma unroll
        for (int mf = 0; mf < 2; ++mf)
#pragma unroll
            for (int nf = 0; nf < 2; ++nf)
#pragma unroll
                for (int ks = 0; ks < 2; ++ks) {
                    acc[mf][nf] = __builtin_amdgcn_mfma_f32_32x32x16_f16(
                        ah[mf][ks], bw[nf][ks], acc[mf][nf], 0, 0, 0);
                    acc[mf][nf] = __builtin_amdgcn_mfma_f32_32x32x16_f16(
                        al8[mf][ks], bw[nf][ks], acc[mf][nf], 0, 0, 0);
                }
    }

    // epilogue: 32x32 C/D layout col = lane&31, row = (reg&3) + 8*(reg>>2) + 4*(lane>>5)
    // [m74/m101 verified, rounds 5-7 proven]
    const size_t t0 = (size_t)bm * 256 + wr * 64;
    const size_t c0 = (size_t)bn * 128 + wc * 64;
#pragma unroll
    for (int mf = 0; mf < 2; ++mf)
#pragma unroll
        for (int nf = 0; nf < 2; ++nf) {
            float* cp = C + (t0 + mf * 32) * RES_DIM + (c0 + nf * 32 + l31);
#pragma unroll
            for (int r = 0; r < 16; ++r) {
                int row = (r & 3) + 8 * (r >> 2) + 4 * kgl;
                cp[(size_t)row * RES_DIM] = acc[mf][nf][r];
            }
        }
}

// ---------- fallback fp32 GEMM (only if ws too small) ----------
__global__ __launch_bounds__(256)
void gemm_f32(const float* __restrict__ A, const float* __restrict__ B, float* __restrict__ C) {
    __shared__ float sAf[64][33];
    __shared__ float sBf[64][33];
    const int tid = threadIdx.x;
    const int tx = tid & 15, ty = tid >> 4;
    const size_t t0 = (size_t)blockIdx.x * 64;
    const size_t r0 = (size_t)blockIdx.y * 64;
    const int lrow = tid >> 2;
    const int lcol = (tid & 3) * 8;
    float acc[4][4] = {};
    for (int k0 = 0; k0 < IN_DIM; k0 += 32) {
        float4 a0 = *(const float4*)&A[(t0 + lrow) * IN_DIM + k0 + lcol];
        float4 a1 = *(const float4*)&A[(t0 + lrow) * IN_DIM + k0 + lcol + 4];
        float4 b0 = *(const float4*)&B[(r0 + lrow) * IN_DIM + k0 + lcol];
        float4 b1 = *(const float4*)&B[(r0 + lrow) * IN_DIM + k0 + lcol + 4];
        __syncthreads();
        sAf[lrow][lcol + 0] = a0.x; sAf[lrow][lcol + 1] = a0.y;
        sAf[lrow][lcol + 2] = a0.z; sAf[lrow][lcol + 3] = a0.w;
        sAf[lrow][lcol + 4] = a1.x; sAf[lrow][lcol + 5] = a1.y;
        sAf[lrow][lcol + 6] = a1.z; sAf[lrow][lcol + 7] = a1.w;
        sBf[lrow][lcol + 0] = b0.x; sBf[lrow][lcol + 1] = b0.y;
        sBf[lrow][lcol + 2] = b0.z; sBf[lrow][lcol + 3] = b0.w;
        sBf[lrow][lcol + 4] = b1.x; sBf[lrow][lcol + 5] = b1.y;
        sBf[lrow][lcol + 6] = b1.z; sBf[lrow][lcol + 7] = b1.w;
        __syncthreads();
#pragma unroll
        for (int kk = 0; kk < 32; ++kk) {
            float av[4], bv[4];
#pragma unroll
            for (int i = 0; i < 4; ++i) av[i] = sAf[ty * 4 + i][kk];
#pragma unroll
            for (int j = 0; j < 4; ++j) bv[j] = sBf[tx * 4 + j][kk];
#pragma unroll
            for (int i = 0; i < 4; ++i)
#pragma unroll
                for (int j = 0; j < 4; ++j) acc[i][j] = fmaf(av[i], bv[j], acc[i][j]);
        }
    }
#pragma unroll
    for (int i = 0; i < 4; ++i)
#pragma unroll
        for (int j = 0; j < 4; ++j)
            C[(t0 + ty * 4 + i) * RES_DIM + r0 + tx * 4 + j] = acc[i][j];
}

// ---------- scan part A: warmup seeds (float2, unchanged from round 6) ----------
__global__ void warmup2_kernel(const float* __restrict__ U, const float* __restrict__ d,
                               float* __restrict__ sinit, int C, int W, int NC) {
    int g = blockIdx.x * blockDim.x + threadIdx.x;
    if (g >= NC * (RES_DIM / 2)) return;
    int c = g >> 11;              // / 2048
    int r2 = g & 2047;
    float2 s = make_float2(0.0f, 0.0f);
    if (c > 0) {
        float2 dr = ((const float2*)d)[r2];
        const float2* p = (const float2*)U + (size_t)(c * C - W) * 2048 + r2;
        constexpr int PF = 8;
        float2 buf[PF];
#pragma unroll
        for (int i = 0; i < PF; ++i) buf[i] = p[(size_t)i * 2048];
        for (int t = 0; t < W; t += PF) {
#pragma unroll
            for (int j = 0; j < PF; ++j) {
                float2 u = buf[j];
                int tn = t + j + PF;
                if (tn < W) buf[j] = p[(size_t)tn * 2048];
                s.x = tanh_fast(fmaf(dr.x, s.x, u.x));
                s.y = tanh_fast(fmaf(dr.y, s.y, u.y));
            }
        }
    }
    ((float2*)sinit)[g] = s;
}

// ---------- scan part B: in-place chunked scan (float2, unchanged from round 6) ----------
__global__ void scan2_kernel(float* __restrict__ U, const float* __restrict__ d,
                             const float* __restrict__ sinit, int C, int NC) {
    int g = blockIdx.x * blockDim.x + threadIdx.x;
    if (g >= NC * (RES_DIM / 2)) return;
    int c = g >> 11;
    int r2 = g & 2047;
    float2 dr = ((const float2*)d)[r2];
    float2 s = (c == 0) ? make_float2(0.0f, 0.0f) : ((const float2*)sinit)[g];
    float2* p = (float2*)U + (size_t)c * C * 2048 + r2;
    constexpr int PF = 8;
    float2 buf[PF];
#pragma unroll
    for (int i = 0; i < PF; ++i) buf[i] = p[(size_t)i * 2048];
    for (int t = 0; t < C; t += PF) {
#pragma unroll
        for (int j = 0; j < PF; ++j) {
            float2 u = buf[j];
            int tn = t + j + PF;
            if (tn < C) buf[j] = p[(size_t)tn * 2048];   // prefetch ahead of the chain
            s.x = tanh_fast(fmaf(dr.x, s.x, u.x));
            s.y = tanh_fast(fmaf(dr.y, s.y, u.y));
            p[(size_t)(t + j) * 2048] = s;
        }
    }
}

// ---------- launch ----------
extern "C" void kernel_launch(void* const* d_in, const int* in_sizes, int n_in,
                              void* d_out, int out_size, void* d_ws, size_t ws_size,
                              hipStream_t stream) {
    const float* x    = (const float*)d_in[0];   // [T, 1024, 1]
    const float* W_in = (const float*)d_in[1];   // [4096, 1024]
    const float* dvec = (const float*)d_in[2];   // [4096]
    float* out = (float*)d_out;                  // [T, 4096]

    constexpr int NC   = 64;
    constexpr int CHK  = T_DIM / NC;   // 128
    constexpr int WARM = 64;

    const size_t szX = (size_t)T_DIM * IN_DIM * sizeof(u16);   // 16 MiB each (hi, lo)
    const size_t szW = (size_t)RES_DIM * IN_DIM * sizeof(u16); // 8 MiB
    const size_t szS = (size_t)NC * RES_DIM * sizeof(float);   // 1 MiB

    if (ws_size >= 2 * szX + szW + szS) {
        u16* Xh = (u16*)d_ws;
        u16* Xl = Xh + (size_t)T_DIM * IN_DIM;
        u16* Wf = Xl + (size_t)T_DIM * IN_DIM;
        float* sinit = (float*)(Wf + (size_t)RES_DIM * IN_DIM);

        convert_f16_pair<<<2048, 256, 0, stream>>>(x, Xh, Xl, T_DIM * IN_DIM / 8);
        convert_f16_single<<<1024, 256, 0, stream>>>(W_in, Wf, RES_DIM * IN_DIM / 8);
        gemm_f16_2p<<<dim3(T_DIM / 256, RES_DIM / 128), 512, 0, stream>>>(Xh, Xl, Wf, out);
        warmup2_kernel<<<NC * (RES_DIM / 2) / 256, 256, 0, stream>>>(out, dvec, sinit, CHK, WARM, NC);
        scan2_kernel<<<NC * (RES_DIM / 2) / 256, 256, 0, stream>>>(out, dvec, sinit, CHK, NC);
    } else {
        gemm_f32<<<dim3(T_DIM / 64, RES_DIM / 64), 256, 0, stream>>>(x, W_in, out);
        if (ws_size >= szS) {
            float* sinit = (float*)d_ws;
            warmup2_kernel<<<NC * (RES_DIM / 2) / 256, 256, 0, stream>>>(out, dvec, sinit, CHK, WARM, NC);
            scan2_kernel<<<NC * (RES_DIM / 2) / 256, 256, 0, stream>>>(out, dvec, sinit, CHK, NC);
        } else {
            scan2_kernel<<<(RES_DIM / 2) / 256, 256, 0, stream>>>(out, dvec, nullptr, T_DIM, 1);
        }
    }
}

// Round 9
// 216.659 us; speedup vs baseline: 1.2568x; 1.0011x over previous
//
#include <hip/hip_runtime.h>
#include <hip/hip_bf16.h>

// Problem constants
#define T_DIM 8192
#define IN_DIM 1024
#define RES_DIM 4096

typedef unsigned short u16;
typedef _Float16 f16;
typedef f16 f16x8 __attribute__((ext_vector_type(8)));
typedef float f32x4 __attribute__((ext_vector_type(4)));
typedef float f32x16 __attribute__((ext_vector_type(16)));

// ---------- helpers ----------
__device__ __forceinline__ float tanh_fast(float z) {
    z = fminf(15.0f, fmaxf(-15.0f, z));          // avoid exp overflow
    float e = __expf(2.0f * z);
    float inv = __builtin_amdgcn_rcpf(e + 1.0f);
    return fmaf(-2.0f, inv, 1.0f);
}

__device__ __forceinline__ void stage16(const u16* g, u16* l) {
    __builtin_amdgcn_global_load_lds(
        (const __attribute__((address_space(1))) void*)g,
        (__attribute__((address_space(3))) void*)l, 16, 0, 0);
}

// ---------- converts: f32 row-major [rows][1024] -> tiled fp16 (verified tile mapping) ----------
// Tile (rt, kt): rows rt*128..+128, k kt*32..+32. In-tile elem = kq*1024 + row*8 + e,
// k = kq*8 + e (kq in [0,4)). Chunk c = ((rt*32+kt)*4+kq)*128 + row.
// For 32x32x16 fragments: kq = ks*2 + (lane>>5) gives k = ks*16 + (lane>>5)*8 + e.
__global__ void convert_f16_pair(const float* __restrict__ src, u16* __restrict__ hi,
                                 u16* __restrict__ lo, int nchunks) {
    for (int c = blockIdx.x * blockDim.x + threadIdx.x; c < nchunks;
         c += gridDim.x * blockDim.x) {
        int row = c & 127;
        int kq  = (c >> 7) & 3;
        int kt  = (c >> 9) & 31;
        int rt  = c >> 14;
        const float* s = src + (size_t)(rt * 128 + row) * 1024 + kt * 32 + kq * 8;
        float4 f0 = *(const float4*)s;
        float4 f1 = *(const float4*)(s + 4);
        float f[8] = {f0.x, f0.y, f0.z, f0.w, f1.x, f1.y, f1.z, f1.w};
        alignas(16) u16 hv[8];
        alignas(16) u16 lv[8];
#pragma unroll
        for (int e = 0; e < 8; ++e) {
            f16 h = (f16)f[e];
            f16 l = (f16)(f[e] - (float)h);
            hv[e] = *(const u16*)&h;
            lv[e] = *(const u16*)&l;
        }
        *(uint4*)(hi + (size_t)c * 8) = *(const uint4*)hv;
        *(uint4*)(lo + (size_t)c * 8) = *(const uint4*)lv;
    }
}

__global__ void convert_f16_single(const float* __restrict__ src, u16* __restrict__ dst,
                                   int nchunks) {
    for (int c = blockIdx.x * blockDim.x + threadIdx.x; c < nchunks;
         c += gridDim.x * blockDim.x) {
        int row = c & 127;
        int kq  = (c >> 7) & 3;
        int kt  = (c >> 9) & 31;
        int rt  = c >> 14;
        const float* s = src + (size_t)(rt * 128 + row) * 1024 + kt * 32 + kq * 8;
        float4 f0 = *(const float4*)s;
        float4 f1 = *(const float4*)(s + 4);
        float f[8] = {f0.x, f0.y, f0.z, f0.w, f1.x, f1.y, f1.z, f1.w};
        alignas(16) u16 hv[8];
#pragma unroll
        for (int e = 0; e < 8; ++e) {
            f16 h = (f16)f[e];
            hv[e] = *(const u16*)&h;
        }
        *(uint4*)(dst + (size_t)c * 8) = *(const uint4*)hv;
    }
}

// ---------- GEMM: 2-pass fp16 MFMA, 128x128 tile / 4 waves / 24 KiB LDS ----------
// Round-1 geometry (best-measured cross-block overlap: 6 resident blocks/CU) with
// round-8's fp16 2-pass math and rounds-5..8's verified 32x32x16 fragment/epilogue
// mappings. Single-buffer 2-barrier loop. Per wave per kt: 12 ds_read_b128 + 16 MFMA.
__global__ __launch_bounds__(256)
void gemm_f16_128(const u16* __restrict__ Xh, const u16* __restrict__ Xl,
                  const u16* __restrict__ Wf, float* __restrict__ C) {
    __shared__ __attribute__((aligned(16))) u16 sAh[4096];
    __shared__ __attribute__((aligned(16))) u16 sAl[4096];
    __shared__ __attribute__((aligned(16))) u16 sW[4096];

    const int tid  = threadIdx.x;
    const int lane = tid & 63;
    const int wave = tid >> 6;
    const int wr = wave >> 1, wc = wave & 1;
    const int bm = blockIdx.x, bn = blockIdx.y;

    f32x16 acc[2][2] = {};   // [mf][nf], each 32x32

    const int l31 = lane & 31;
    const int kgl = lane >> 5;

    const size_t abase = (size_t)bm * 32 * 4096;
    const size_t bbase = (size_t)bn * 32 * 4096;

    for (int kt = 0; kt < 32; ++kt) {
        const u16* gXh = Xh + abase + (size_t)kt * 4096;
        const u16* gXl = Xl + abase + (size_t)kt * 4096;
        const u16* gW  = Wf + bbase + (size_t)kt * 4096;
        __syncthreads();   // previous iteration's LDS reads done (WAR)
#pragma unroll
        for (int i = 0; i < 2; ++i) {
            int c  = tid + i * 256;       // chunk in [0,512)
            int wb = (c & ~63) * 8;       // wave-uniform LDS elem base
            int ge = c * 8;               // per-lane global elem offset
            stage16(gXh + ge, sAh + wb);
            stage16(gXl + ge, sAl + wb);
            stage16(gW  + ge, sW  + wb);
        }
        __syncthreads();   // staging visible (compiler drains vmcnt at barrier)

        f16x8 ah[2][2], al8[2][2], bw[2][2];   // [mf|nf][ks]
#pragma unroll
        for (int mf = 0; mf < 2; ++mf)
#pragma unroll
            for (int ks = 0; ks < 2; ++ks) {
                int ao = (ks * 2 + kgl) * 1024 + (wr * 64 + mf * 32 + l31) * 8;
                ah[mf][ks]  = *(const f16x8*)(sAh + ao);
                al8[mf][ks] = *(const f16x8*)(sAl + ao);
            }
#pragma unroll
        for (int nf = 0; nf < 2; ++nf)
#pragma unroll
            for (int ks = 0; ks < 2; ++ks) {
                int bo = (ks * 2 + kgl) * 1024 + (wc * 64 + nf * 32 + l31) * 8;
                bw[nf][ks] = *(const f16x8*)(sW + bo);
            }
#pragma unroll
        for (int mf = 0; mf < 2; ++mf)
#pragma unroll
            for (int nf = 0; nf < 2; ++nf)
#pragma unroll
                for (int ks = 0; ks < 2; ++ks) {
                    acc[mf][nf] = __builtin_amdgcn_mfma_f32_32x32x16_f16(
                        ah[mf][ks], bw[nf][ks], acc[mf][nf], 0, 0, 0);
                    acc[mf][nf] = __builtin_amdgcn_mfma_f32_32x32x16_f16(
                        al8[mf][ks], bw[nf][ks], acc[mf][nf], 0, 0, 0);
                }
    }

    // epilogue: 32x32 C/D layout col = lane&31, row = (reg&3) + 8*(reg>>2) + 4*(lane>>5)
    // [m74/m101 verified, rounds 5-8 proven]
    const size_t t0 = (size_t)bm * 128 + wr * 64;
    const size_t c0 = (size_t)bn * 128 + wc * 64;
#pragma unroll
    for (int mf = 0; mf < 2; ++mf)
#pragma unroll
        for (int nf = 0; nf < 2; ++nf) {
            float* cp = C + (t0 + mf * 32) * RES_DIM + (c0 + nf * 32 + l31);
#pragma unroll
            for (int r = 0; r < 16; ++r) {
                int row = (r & 3) + 8 * (r >> 2) + 4 * kgl;
                cp[(size_t)row * RES_DIM] = acc[mf][nf][r];
            }
        }
}

// ---------- fallback fp32 GEMM (only if ws too small) ----------
__global__ __launch_bounds__(256)
void gemm_f32(const float* __restrict__ A, const float* __restrict__ B, float* __restrict__ C) {
    __shared__ float sAf[64][33];
    __shared__ float sBf[64][33];
    const int tid = threadIdx.x;
    const int tx = tid & 15, ty = tid >> 4;
    const size_t t0 = (size_t)blockIdx.x * 64;
    const size_t r0 = (size_t)blockIdx.y * 64;
    const int lrow = tid >> 2;
    const int lcol = (tid & 3) * 8;
    float acc[4][4] = {};
    for (int k0 = 0; k0 < IN_DIM; k0 += 32) {
        float4 a0 = *(const float4*)&A[(t0 + lrow) * IN_DIM + k0 + lcol];
        float4 a1 = *(const float4*)&A[(t0 + lrow) * IN_DIM + k0 + lcol + 4];
        float4 b0 = *(const float4*)&B[(r0 + lrow) * IN_DIM + k0 + lcol];
        float4 b1 = *(const float4*)&B[(r0 + lrow) * IN_DIM + k0 + lcol + 4];
        __syncthreads();
        sAf[lrow][lcol + 0] = a0.x; sAf[lrow][lcol + 1] = a0.y;
        sAf[lrow][lcol + 2] = a0.z; sAf[lrow][lcol + 3] = a0.w;
        sAf[lrow][lcol + 4] = a1.x; sAf[lrow][lcol + 5] = a1.y;
        sAf[lrow][lcol + 6] = a1.z; sAf[lrow][lcol + 7] = a1.w;
        sBf[lrow][lcol + 0] = b0.x; sBf[lrow][lcol + 1] = b0.y;
        sBf[lrow][lcol + 2] = b0.z; sBf[lrow][lcol + 3] = b0.w;
        sBf[lrow][lcol + 4] = b1.x; sBf[lrow][lcol + 5] = b1.y;
        sBf[lrow][lcol + 6] = b1.z; sBf[lrow][lcol + 7] = b1.w;
        __syncthreads();
#pragma unroll
        for (int kk = 0; kk < 32; ++kk) {
            float av[4], bv[4];
#pragma unroll
            for (int i = 0; i < 4; ++i) av[i] = sAf[ty * 4 + i][kk];
#pragma unroll
            for (int j = 0; j < 4; ++j) bv[j] = sBf[tx * 4 + j][kk];
#pragma unroll
            for (int i = 0; i < 4; ++i)
#pragma unroll
                for (int j = 0; j < 4; ++j) acc[i][j] = fmaf(av[i], bv[j], acc[i][j]);
        }
    }
#pragma unroll
    for (int i = 0; i < 4; ++i)
#pragma unroll
        for (int j = 0; j < 4; ++j)
            C[(t0 + ty * 4 + i) * RES_DIM + r0 + tx * 4 + j] = acc[i][j];
}

// ---------- scan part A: warmup seeds (float2, unchanged from rounds 6-8) ----------
__global__ void warmup2_kernel(const float* __restrict__ U, const float* __restrict__ d,
                               float* __restrict__ sinit, int C, int W, int NC) {
    int g = blockIdx.x * blockDim.x + threadIdx.x;
    if (g >= NC * (RES_DIM / 2)) return;
    int c = g >> 11;              // / 2048
    int r2 = g & 2047;
    float2 s = make_float2(0.0f, 0.0f);
    if (c > 0) {
        float2 dr = ((const float2*)d)[r2];
        const float2* p = (const float2*)U + (size_t)(c * C - W) * 2048 + r2;
        constexpr int PF = 8;
        float2 buf[PF];
#pragma unroll
        for (int i = 0; i < PF; ++i) buf[i] = p[(size_t)i * 2048];
        for (int t = 0; t < W; t += PF) {
#pragma unroll
            for (int j = 0; j < PF; ++j) {
                float2 u = buf[j];
                int tn = t + j + PF;
                if (tn < W) buf[j] = p[(size_t)tn * 2048];
                s.x = tanh_fast(fmaf(dr.x, s.x, u.x));
                s.y = tanh_fast(fmaf(dr.y, s.y, u.y));
            }
        }
    }
    ((float2*)sinit)[g] = s;
}

// ---------- scan part B: in-place chunked scan (float2, unchanged from rounds 6-8) ----------
__global__ void scan2_kernel(float* __restrict__ U, const float* __restrict__ d,
                             const float* __restrict__ sinit, int C, int NC) {
    int g = blockIdx.x * blockDim.x + threadIdx.x;
    if (g >= NC * (RES_DIM / 2)) return;
    int c = g >> 11;
    int r2 = g & 2047;
    float2 dr = ((const float2*)d)[r2];
    float2 s = (c == 0) ? make_float2(0.0f, 0.0f) : ((const float2*)sinit)[g];
    float2* p = (float2*)U + (size_t)c * C * 2048 + r2;
    constexpr int PF = 8;
    float2 buf[PF];
#pragma unroll
    for (int i = 0; i < PF; ++i) buf[i] = p[(size_t)i * 2048];
    for (int t = 0; t < C; t += PF) {
#pragma unroll
        for (int j = 0; j < PF; ++j) {
            float2 u = buf[j];
            int tn = t + j + PF;
            if (tn < C) buf[j] = p[(size_t)tn * 2048];   // prefetch ahead of the chain
            s.x = tanh_fast(fmaf(dr.x, s.x, u.x));
            s.y = tanh_fast(fmaf(dr.y, s.y, u.y));
            p[(size_t)(t + j) * 2048] = s;
        }
    }
}

// ---------- launch ----------
extern "C" void kernel_launch(void* const* d_in, const int* in_sizes, int n_in,
                              void* d_out, int out_size, void* d_ws, size_t ws_size,
                              hipStream_t stream) {
    const float* x    = (const float*)d_in[0];   // [T, 1024, 1]
    const float* W_in = (const float*)d_in[1];   // [4096, 1024]
    const float* dvec = (const float*)d_in[2];   // [4096]
    float* out = (float*)d_out;                  // [T, 4096]

    constexpr int NC   = 64;
    constexpr int CHK  = T_DIM / NC;   // 128
    constexpr int WARM = 64;

    const size_t szX = (size_t)T_DIM * IN_DIM * sizeof(u16);   // 16 MiB each (hi, lo)
    const size_t szW = (size_t)RES_DIM * IN_DIM * sizeof(u16); // 8 MiB
    const size_t szS = (size_t)NC * RES_DIM * sizeof(float);   // 1 MiB

    if (ws_size >= 2 * szX + szW + szS) {
        u16* Xh = (u16*)d_ws;
        u16* Xl = Xh + (size_t)T_DIM * IN_DIM;
        u16* Wf = Xl + (size_t)T_DIM * IN_DIM;
        float* sinit = (float*)(Wf + (size_t)RES_DIM * IN_DIM);

        convert_f16_pair<<<2048, 256, 0, stream>>>(x, Xh, Xl, T_DIM * IN_DIM / 8);
        convert_f16_single<<<1024, 256, 0, stream>>>(W_in, Wf, RES_DIM * IN_DIM / 8);
        gemm_f16_128<<<dim3(T_DIM / 128, RES_DIM / 128), 256, 0, stream>>>(Xh, Xl, Wf, out);
        warmup2_kernel<<<NC * (RES_DIM / 2) / 256, 256, 0, stream>>>(out, dvec, sinit, CHK, WARM, NC);
        scan2_kernel<<<NC * (RES_DIM / 2) / 256, 256, 0, stream>>>(out, dvec, sinit, CHK, NC);
    } else {
        gemm_f32<<<dim3(T_DIM / 64, RES_DIM / 64), 256, 0, stream>>>(x, W_in, out);
        if (ws_size >= szS) {
            float* sinit = (float*)d_ws;
            warmup2_kernel<<<NC * (RES_DIM / 2) / 256, 256, 0, stream>>>(out, dvec, sinit, CHK, WARM, NC);
            scan2_kernel<<<NC * (RES_DIM / 2) / 256, 256, 0, stream>>>(out, dvec, sinit, CHK, NC);
        } else {
            scan2_kernel<<<(RES_DIM / 2) / 256, 256, 0, stream>>>(out, dvec, nullptr, T_DIM, 1);
        }
    }
}

// Round 10
// 204.088 us; speedup vs baseline: 1.3342x; 1.0616x over previous
//
#include <hip/hip_runtime.h>
#include <hip/hip_bf16.h>

// Problem constants
#define T_DIM 8192
#define IN_DIM 1024
#define RES_DIM 4096

typedef unsigned short u16;
typedef _Float16 f16;
typedef f16 f16x8 __attribute__((ext_vector_type(8)));
typedef float f32x4 __attribute__((ext_vector_type(4)));
typedef float f32x16 __attribute__((ext_vector_type(16)));

// ---------- helpers ----------
__device__ __forceinline__ float tanh_fast(float z) {
    z = fminf(15.0f, fmaxf(-15.0f, z));          // avoid exp overflow
    float e = __expf(2.0f * z);
    float inv = __builtin_amdgcn_rcpf(e + 1.0f);
    return fmaf(-2.0f, inv, 1.0f);
}

__device__ __forceinline__ void stage16(const u16* g, u16* l) {
    __builtin_amdgcn_global_load_lds(
        (const __attribute__((address_space(1))) void*)g,
        (__attribute__((address_space(3))) void*)l, 16, 0, 0);
}

// ---------- converts: f32 row-major [rows][1024] -> tiled fp16 (verified tile mapping) ----------
// Tile (rt, kt): rows rt*128..+128, k kt*32..+32. In-tile elem = kq*1024 + row*8 + e,
// k = kq*8 + e (kq in [0,4)). Chunk c = ((rt*32+kt)*4+kq)*128 + row.
// For 32x32x16 fragments: kq = ks*2 + (lane>>5) gives k = ks*16 + (lane>>5)*8 + e.
__global__ void convert_f16_pair(const float* __restrict__ src, u16* __restrict__ hi,
                                 u16* __restrict__ lo, int nchunks) {
    for (int c = blockIdx.x * blockDim.x + threadIdx.x; c < nchunks;
         c += gridDim.x * blockDim.x) {
        int row = c & 127;
        int kq  = (c >> 7) & 3;
        int kt  = (c >> 9) & 31;
        int rt  = c >> 14;
        const float* s = src + (size_t)(rt * 128 + row) * 1024 + kt * 32 + kq * 8;
        float4 f0 = *(const float4*)s;
        float4 f1 = *(const float4*)(s + 4);
        float f[8] = {f0.x, f0.y, f0.z, f0.w, f1.x, f1.y, f1.z, f1.w};
        alignas(16) u16 hv[8];
        alignas(16) u16 lv[8];
#pragma unroll
        for (int e = 0; e < 8; ++e) {
            f16 h = (f16)f[e];
            f16 l = (f16)(f[e] - (float)h);
            hv[e] = *(const u16*)&h;
            lv[e] = *(const u16*)&l;
        }
        *(uint4*)(hi + (size_t)c * 8) = *(const uint4*)hv;
        *(uint4*)(lo + (size_t)c * 8) = *(const uint4*)lv;
    }
}

__global__ void convert_f16_single(const float* __restrict__ src, u16* __restrict__ dst,
                                   int nchunks) {
    for (int c = blockIdx.x * blockDim.x + threadIdx.x; c < nchunks;
         c += gridDim.x * blockDim.x) {
        int row = c & 127;
        int kq  = (c >> 7) & 3;
        int kt  = (c >> 9) & 31;
        int rt  = c >> 14;
        const float* s = src + (size_t)(rt * 128 + row) * 1024 + kt * 32 + kq * 8;
        float4 f0 = *(const float4*)s;
        float4 f1 = *(const float4*)(s + 4);
        float f[8] = {f0.x, f0.y, f0.z, f0.w, f1.x, f1.y, f1.z, f1.w};
        alignas(16) u16 hv[8];
#pragma unroll
        for (int e = 0; e < 8; ++e) {
            f16 h = (f16)f[e];
            hv[e] = *(const u16*)&h;
        }
        *(uint4*)(dst + (size_t)c * 8) = *(const uint4*)hv;
    }
}

// ---------- GEMM: 2-pass fp16 MFMA, 128x256 tile, 64x128 wave blocks ----------
// LDS-traffic-reduction geometry: 4 waves (2M x 2N), each computing 64x128 via
// 2x4 32x32 fragments (acc = 128 VGPR). Per-output LDS reads drop 3.0 -> 2.0 B/kt
// (A amp 2x, W amp 2x). Proven single-buffer 2-barrier loop; verified tiled layout
// (W tile = 2 row-tiles, staged like round-6 A), fragment & epilogue mappings.
// Per wave per kt: 16 ds_read_b128 + 32 MFMA. LDS 32 KiB.
__global__ __launch_bounds__(256)
void gemm_f16_wide(const u16* __restrict__ Xh, const u16* __restrict__ Xl,
                   const u16* __restrict__ Wf, float* __restrict__ C) {
    __shared__ __attribute__((aligned(16))) u16 sAh[4096];
    __shared__ __attribute__((aligned(16))) u16 sAl[4096];
    __shared__ __attribute__((aligned(16))) u16 sW[2][4096];

    const int tid  = threadIdx.x;
    const int lane = tid & 63;
    const int wave = tid >> 6;
    const int wr = wave >> 1, wc = wave & 1;
    const int bm = blockIdx.x, bn = blockIdx.y;

    f32x16 acc[2][4] = {};   // [mf][nf], each 32x32

    const int l31 = lane & 31;
    const int kgl = lane >> 5;

    for (int kt = 0; kt < 32; ++kt) {
        const u16* gX0 = Xh + ((size_t)(bm * 32 + kt)) * 4096;
        const u16* gX1 = Xl + ((size_t)(bm * 32 + kt)) * 4096;
        const u16* gW0 = Wf + ((size_t)((bn * 2 + 0) * 32 + kt)) * 4096;
        const u16* gW1 = Wf + ((size_t)((bn * 2 + 1) * 32 + kt)) * 4096;
        __syncthreads();   // previous iteration's LDS reads done (WAR)
#pragma unroll
        for (int i = 0; i < 2; ++i) {
            int off = i * 2048 + tid * 8;          // per-lane global elem offset
            int wb  = i * 2048 + (tid & ~63) * 8;  // wave-uniform LDS elem base
            stage16(gX0 + off, sAh + wb);
            stage16(gX1 + off, sAl + wb);
            stage16(gW0 + off, &sW[0][0] + wb);
            stage16(gW1 + off, &sW[1][0] + wb);
        }
        __syncthreads();   // staging visible (compiler drains vmcnt at barrier)

        f16x8 ah[2][2], al8[2][2], bw[4][2];   // [mf|nf][ks]
#pragma unroll
        for (int mf = 0; mf < 2; ++mf)
#pragma unroll
            for (int ks = 0; ks < 2; ++ks) {
                int ao = (ks * 2 + kgl) * 1024 + (wr * 64 + mf * 32 + l31) * 8;
                ah[mf][ks]  = *(const f16x8*)(sAh + ao);
                al8[mf][ks] = *(const f16x8*)(sAl + ao);
            }
#pragma unroll
        for (int nf = 0; nf < 4; ++nf)
#pragma unroll
            for (int ks = 0; ks < 2; ++ks) {
                int bo = (ks * 2 + kgl) * 1024 + (nf * 32 + l31) * 8;
                bw[nf][ks] = *(const f16x8*)(&sW[wc][0] + bo);
            }
#pragma unroll
        for (int mf = 0; mf < 2; ++mf)
#pragma unroll
            for (int nf = 0; nf < 4; ++nf)
#pragma unroll
                for (int ks = 0; ks < 2; ++ks) {
                    acc[mf][nf] = __builtin_amdgcn_mfma_f32_32x32x16_f16(
                        ah[mf][ks], bw[nf][ks], acc[mf][nf], 0, 0, 0);
                    acc[mf][nf] = __builtin_amdgcn_mfma_f32_32x32x16_f16(
                        al8[mf][ks], bw[nf][ks], acc[mf][nf], 0, 0, 0);
                }
    }

    // epilogue: 32x32 C/D layout col = lane&31, row = (reg&3) + 8*(reg>>2) + 4*(lane>>5)
    // [m74/m101 verified, rounds 5-9 proven]
    const size_t t0 = (size_t)bm * 128 + wr * 64;
    const size_t c0 = (size_t)bn * 256 + wc * 128;
#pragma unroll
    for (int mf = 0; mf < 2; ++mf)
#pragma unroll
        for (int nf = 0; nf < 4; ++nf) {
            float* cp = C + (t0 + mf * 32) * RES_DIM + (c0 + nf * 32 + l31);
#pragma unroll
            for (int r = 0; r < 16; ++r) {
                int row = (r & 3) + 8 * (r >> 2) + 4 * kgl;
                cp[(size_t)row * RES_DIM] = acc[mf][nf][r];
            }
        }
}

// ---------- fallback fp32 GEMM (only if ws too small) ----------
__global__ __launch_bounds__(256)
void gemm_f32(const float* __restrict__ A, const float* __restrict__ B, float* __restrict__ C) {
    __shared__ float sAf[64][33];
    __shared__ float sBf[64][33];
    const int tid = threadIdx.x;
    const int tx = tid & 15, ty = tid >> 4;
    const size_t t0 = (size_t)blockIdx.x * 64;
    const size_t r0 = (size_t)blockIdx.y * 64;
    const int lrow = tid >> 2;
    const int lcol = (tid & 3) * 8;
    float acc[4][4] = {};
    for (int k0 = 0; k0 < IN_DIM; k0 += 32) {
        float4 a0 = *(const float4*)&A[(t0 + lrow) * IN_DIM + k0 + lcol];
        float4 a1 = *(const float4*)&A[(t0 + lrow) * IN_DIM + k0 + lcol + 4];
        float4 b0 = *(const float4*)&B[(r0 + lrow) * IN_DIM + k0 + lcol];
        float4 b1 = *(const float4*)&B[(r0 + lrow) * IN_DIM + k0 + lcol + 4];
        __syncthreads();
        sAf[lrow][lcol + 0] = a0.x; sAf[lrow][lcol + 1] = a0.y;
        sAf[lrow][lcol + 2] = a0.z; sAf[lrow][lcol + 3] = a0.w;
        sAf[lrow][lcol + 4] = a1.x; sAf[lrow][lcol + 5] = a1.y;
        sAf[lrow][lcol + 6] = a1.z; sAf[lrow][lcol + 7] = a1.w;
        sBf[lrow][lcol + 0] = b0.x; sBf[lrow][lcol + 1] = b0.y;
        sBf[lrow][lcol + 2] = b0.z; sBf[lrow][lcol + 3] = b0.w;
        sBf[lrow][lcol + 4] = b1.x; sBf[lrow][lcol + 5] = b1.y;
        sBf[lrow][lcol + 6] = b1.z; sBf[lrow][lcol + 7] = b1.w;
        __syncthreads();
#pragma unroll
        for (int kk = 0; kk < 32; ++kk) {
            float av[4], bv[4];
#pragma unroll
            for (int i = 0; i < 4; ++i) av[i] = sAf[ty * 4 + i][kk];
#pragma unroll
            for (int j = 0; j < 4; ++j) bv[j] = sBf[tx * 4 + j][kk];
#pragma unroll
            for (int i = 0; i < 4; ++i)
#pragma unroll
                for (int j = 0; j < 4; ++j) acc[i][j] = fmaf(av[i], bv[j], acc[i][j]);
        }
    }
#pragma unroll
    for (int i = 0; i < 4; ++i)
#pragma unroll
        for (int j = 0; j < 4; ++j)
            C[(t0 + ty * 4 + i) * RES_DIM + r0 + tx * 4 + j] = acc[i][j];
}

// ---------- scan part A: warmup seeds (float2, unchanged from rounds 6-9) ----------
__global__ void warmup2_kernel(const float* __restrict__ U, const float* __restrict__ d,
                               float* __restrict__ sinit, int C, int W, int NC) {
    int g = blockIdx.x * blockDim.x + threadIdx.x;
    if (g >= NC * (RES_DIM / 2)) return;
    int c = g >> 11;              // / 2048
    int r2 = g & 2047;
    float2 s = make_float2(0.0f, 0.0f);
    if (c > 0) {
        float2 dr = ((const float2*)d)[r2];
        const float2* p = (const float2*)U + (size_t)(c * C - W) * 2048 + r2;
        constexpr int PF = 8;
        float2 buf[PF];
#pragma unroll
        for (int i = 0; i < PF; ++i) buf[i] = p[(size_t)i * 2048];
        for (int t = 0; t < W; t += PF) {
#pragma unroll
            for (int j = 0; j < PF; ++j) {
                float2 u = buf[j];
                int tn = t + j + PF;
                if (tn < W) buf[j] = p[(size_t)tn * 2048];
                s.x = tanh_fast(fmaf(dr.x, s.x, u.x));
                s.y = tanh_fast(fmaf(dr.y, s.y, u.y));
            }
        }
    }
    ((float2*)sinit)[g] = s;
}

// ---------- scan part B: in-place chunked scan (float2, unchanged from rounds 6-9) ----------
__global__ void scan2_kernel(float* __restrict__ U, const float* __restrict__ d,
                             const float* __restrict__ sinit, int C, int NC) {
    int g = blockIdx.x * blockDim.x + threadIdx.x;
    if (g >= NC * (RES_DIM / 2)) return;
    int c = g >> 11;
    int r2 = g & 2047;
    float2 dr = ((const float2*)d)[r2];
    float2 s = (c == 0) ? make_float2(0.0f, 0.0f) : ((const float2*)sinit)[g];
    float2* p = (float2*)U + (size_t)c * C * 2048 + r2;
    constexpr int PF = 8;
    float2 buf[PF];
#pragma unroll
    for (int i = 0; i < PF; ++i) buf[i] = p[(size_t)i * 2048];
    for (int t = 0; t < C; t += PF) {
#pragma unroll
        for (int j = 0; j < PF; ++j) {
            float2 u = buf[j];
            int tn = t + j + PF;
            if (tn < C) buf[j] = p[(size_t)tn * 2048];   // prefetch ahead of the chain
            s.x = tanh_fast(fmaf(dr.x, s.x, u.x));
            s.y = tanh_fast(fmaf(dr.y, s.y, u.y));
            p[(size_t)(t + j) * 2048] = s;
        }
    }
}

// ---------- launch ----------
extern "C" void kernel_launch(void* const* d_in, const int* in_sizes, int n_in,
                              void* d_out, int out_size, void* d_ws, size_t ws_size,
                              hipStream_t stream) {
    const float* x    = (const float*)d_in[0];   // [T, 1024, 1]
    const float* W_in = (const float*)d_in[1];   // [4096, 1024]
    const float* dvec = (const float*)d_in[2];   // [4096]
    float* out = (float*)d_out;                  // [T, 4096]

    constexpr int NC   = 64;
    constexpr int CHK  = T_DIM / NC;   // 128
    constexpr int WARM = 64;

    const size_t szX = (size_t)T_DIM * IN_DIM * sizeof(u16);   // 16 MiB each (hi, lo)
    const size_t szW = (size_t)RES_DIM * IN_DIM * sizeof(u16); // 8 MiB
    const size_t szS = (size_t)NC * RES_DIM * sizeof(float);   // 1 MiB

    if (ws_size >= 2 * szX + szW + szS) {
        u16* Xh = (u16*)d_ws;
        u16* Xl = Xh + (size_t)T_DIM * IN_DIM;
        u16* Wf = Xl + (size_t)T_DIM * IN_DIM;
        float* sinit = (float*)(Wf + (size_t)RES_DIM * IN_DIM);

        convert_f16_pair<<<2048, 256, 0, stream>>>(x, Xh, Xl, T_DIM * IN_DIM / 8);
        convert_f16_single<<<1024, 256, 0, stream>>>(W_in, Wf, RES_DIM * IN_DIM / 8);
        gemm_f16_wide<<<dim3(T_DIM / 128, RES_DIM / 256), 256, 0, stream>>>(Xh, Xl, Wf, out);
        warmup2_kernel<<<NC * (RES_DIM / 2) / 256, 256, 0, stream>>>(out, dvec, sinit, CHK, WARM, NC);
        scan2_kernel<<<NC * (RES_DIM / 2) / 256, 256, 0, stream>>>(out, dvec, sinit, CHK, NC);
    } else {
        gemm_f32<<<dim3(T_DIM / 64, RES_DIM / 64), 256, 0, stream>>>(x, W_in, out);
        if (ws_size >= szS) {
            float* sinit = (float*)d_ws;
            warmup2_kernel<<<NC * (RES_DIM / 2) / 256, 256, 0, stream>>>(out, dvec, sinit, CHK, WARM, NC);
            scan2_kernel<<<NC * (RES_DIM / 2) / 256, 256, 0, stream>>>(out, dvec, sinit, CHK, NC);
        } else {
            scan2_kernel<<<(RES_DIM / 2) / 256, 256, 0, stream>>>(out, dvec, nullptr, T_DIM, 1);
        }
    }
}